// Round 18
// baseline (257.112 us; speedup 1.0000x reference)
//
#include <hip/hip_runtime.h>
#include <hip/hip_fp16.h>
#include <math.h>

#define N_NODES 50000
#define NPAD    50048
#define N_EDGES 800000
#define F_IN    128
#define HC      64
#define NG      128
#define NCLS    10
#define NXT     782      // ceil(N_NODES/64) row tiles
#define XCHUNK  98       // ceil(NXT/8) tiles per XCD
#define DRANGE  6250     // N_NODES / 8 dst-range per XCD group
#define SCB     2048     // ELL-build block count (multiple of 8)
#define MAXDEG  64       // ELL row capacity (Poisson(16) max over 50k ~ 45)

typedef __attribute__((ext_vector_type(8))) _Float16 f16x8;  // 8 fp16 (4 VGPR)
typedef __attribute__((ext_vector_type(4))) float f32x4;
typedef _Float16 half2v __attribute__((ext_vector_type(2)));

__device__ __forceinline__ float fdot2_acc(unsigned a, unsigned b, float c) {
#if __has_builtin(__builtin_amdgcn_fdot2)
    half2v ha, hb;
    __builtin_memcpy(&ha, &a, 4);
    __builtin_memcpy(&hb, &b, 4);
    return __builtin_amdgcn_fdot2(ha, hb, c, false);
#else
    __half2 ha = *(__half2*)&a, hb = *(__half2*)&b;
    return c + __low2float(ha) * __low2float(hb) + __high2float(ha) * __high2float(hb);
#endif
}

// ================= ELL adjacency build (single pass) =================
// (R17 evidence: deg-line padding was a null result — the build is at its atomic
//  issue/latency floor. DPAD reverted to 1; the 3.2 MB memset cost 42 us/replay.)
__device__ __forceinline__ void ell_body(int bid, const int* __restrict__ src,
                                         const int* __restrict__ dst,
                                         int* __restrict__ deg,
                                         int* __restrict__ slots) {
    int grp = bid & 7;
    int nb = SCB >> 3;
    int slot = bid >> 3;
    int lo = grp * DRANGE, hi = lo + DRANGE;
    const int4* d4p = (const int4*)dst;
    const int4* s4p = (const int4*)src;
    int nchunks = N_EDGES >> 2;
    for (int t = slot * 256 + (int)threadIdx.x; t < nchunks; t += nb * 256) {
        int4 d = d4p[t];
        bool v0 = (d.x >= lo && d.x < hi);
        bool v1 = (d.y >= lo && d.y < hi);
        bool v2 = (d.z >= lo && d.z < hi);
        bool v3 = (d.w >= lo && d.w < hi);
        if (!(v0 | v1 | v2 | v3)) continue;
        int4 s = s4p[t];
        if (v0) { int r = atomicAdd(&deg[d.x], 1); if (r < MAXDEG) slots[d.x * MAXDEG + r] = s.x; }
        if (v1) { int r = atomicAdd(&deg[d.y], 1); if (r < MAXDEG) slots[d.y * MAXDEG + r] = s.y; }
        if (v2) { int r = atomicAdd(&deg[d.z], 1); if (r < MAXDEG) slots[d.z * MAXDEG + r] = s.z; }
        if (v3) { int r = atomicAdd(&deg[d.w], 1); if (r < MAXDEG) slots[d.w * MAXDEG + r] = s.w; }
    }
}

// merged: ELL build + weight conversion + x cast (all independent)
__global__ __launch_bounds__(256) void ellconv_kernel(
    const int* __restrict__ src, const int* __restrict__ dst,
    int* __restrict__ deg, int* __restrict__ slots,
    const float* __restrict__ x, unsigned short* __restrict__ xf16, int n4x,
    const float* __restrict__ W10, const float* __restrict__ W11,
    const float* __restrict__ W12, const float* __restrict__ W13,
    const float* __restrict__ W20, const float* __restrict__ W21,
    const float* __restrict__ W22, const float* __restrict__ W23,
    const float* __restrict__ W30, const float* __restrict__ W31,
    const float* __restrict__ W32, const float* __restrict__ W33,
    unsigned short* __restrict__ wt_h)
{
    int bid = blockIdx.x;
    if (bid < SCB) {
        ell_body(bid, src, dst, deg, slots);
    } else if (bid < SCB + 256) {
        int idx = (bid - SCB) * 256 + threadIdx.x;   // [0, 65536)
        const float* W;
        int K, dbase, rr;
        if (idx < 32768) {
            int mat = idx >> 13; rr = idx & 8191; K = 128;
            W = (mat == 0) ? W10 : (mat == 1) ? W11 : (mat == 2) ? W12 : W13;
            dbase = 0 * 32768 + mat * 8192;
        } else if (idx < 49152) {
            int i2 = idx - 32768;
            int mat = i2 >> 12; rr = i2 & 4095; K = 64;
            W = (mat == 0) ? W20 : (mat == 1) ? W21 : (mat == 2) ? W22 : W23;
            dbase = 1 * 32768 + mat * 4096;
        } else {
            int i3 = idx - 49152;
            int mat = i3 >> 12; rr = i3 & 4095; K = 64;
            W = (mat == 0) ? W30 : (mat == 1) ? W31 : (mat == 2) ? W32 : W33;
            dbase = 2 * 32768 + mat * 4096;
        }
        int k = rr >> 6, c = rr & 63;
        float f = W[k * 64 + c];
        wt_h[dbase + c * K + k] = __half_as_ushort(__float2half_rn(f));
    } else {
        int t = (bid - SCB - 256) * 256 + threadIdx.x;
        if (t < n4x) {
            float4 f = ((const float4*)x)[t];
            ushort4 u;
            u.x = __half_as_ushort(__float2half_rn(f.x));
            u.y = __half_as_ushort(__float2half_rn(f.y));
            u.z = __half_as_ushort(__float2half_rn(f.z));
            u.w = __half_as_ushort(__float2half_rn(f.w));
            ((ushort4*)xf16)[t] = u;
        }
    }
}

// ================= fused-y fp16 MFMA GEMM: one block per row-tile =================
__global__ __launch_bounds__(256) void mfma_gemm_kernel(
    const unsigned short* __restrict__ A16, const unsigned short* __restrict__ Wt_h,
    const float* __restrict__ b0, const float* __restrict__ b1,
    const float* __restrict__ b2, const float* __restrict__ b3,
    unsigned short* __restrict__ qp16, unsigned short* __restrict__ sf16,
    unsigned short* __restrict__ kvpk, int M, int K)
{
    extern __shared__ char smem[];
    int bid = blockIdx.x;
    int xcd = bid & 7;
    int slot = bid >> 3;
    int xt = xcd * XCHUNK + slot;
    if (xt >= NXT) return;
    int row0 = xt * 64;

    const int tileB = 64 * K * 2;
    char* sA = smem;
    char* sB = smem + tileB;

    int tid = threadIdx.x;
    int cpr = K >> 3;
    int total = 64 * cpr;

    const f16x8* gA = (const f16x8*)(A16 + (size_t)row0 * K);
    for (int t = tid; t < total; t += 256) {
        int row = t / cpr, cs = t - row * cpr;
        int dstB = row * (K * 2) + ((cs * 16) ^ ((row & 7) << 4));
        *(f16x8*)(sA + dstB) = gA[t];
    }

    int w = tid >> 6, lane = tid & 63, lr = lane & 15, kq = lane >> 4;
    int arow = w * 16 + lr;
    int abase = arow * (K * 2);
    int aswz = (arow & 7) << 4;

    for (int y = 0; y < 4; ++y) {
        const f16x8* gB = (const f16x8*)(Wt_h + (size_t)y * 64 * K);
        for (int t = tid; t < total; t += 256) {
            int row = t / cpr, cs = t - row * cpr;
            int dstB = row * (K * 2) + ((cs * 16) ^ ((row & 7) << 4));
            *(f16x8*)(sB + dstB) = gB[t];
        }
        __syncthreads();

        f32x4 acc[4];
        #pragma unroll
        for (int f = 0; f < 4; ++f) acc[f] = (f32x4){0.f, 0.f, 0.f, 0.f};
        for (int ks = 0; ks < K; ks += 32) {
            int kb = ks * 2 + kq * 16;
            f16x8 a = *(const f16x8*)(sA + abase + (kb ^ aswz));
            #pragma unroll
            for (int f = 0; f < 4; ++f) {
                int brow = f * 16 + lr;
                int boff = brow * (K * 2) + (kb ^ ((brow & 7) << 4));
                f16x8 bh = *(const f16x8*)(sB + boff);
                acc[f] = __builtin_amdgcn_mfma_f32_16x16x32_f16(a, bh, acc[f], 0, 0, 0);
            }
        }

        const float* bias = (y == 0) ? b0 : (y == 1) ? b1 : (y == 2) ? b2 : b3;
        if (y == 0 || y == 3) {
            unsigned short* dstp = (y == 0) ? qp16 : sf16;
            #pragma unroll
            for (int f = 0; f < 4; ++f) {
                float bv = bias[f * 16 + lr];
                #pragma unroll
                for (int r = 0; r < 4; ++r) {
                    int gr = row0 + w * 16 + kq * 4 + r;
                    if (gr < M)
                        dstp[(size_t)gr * 64 + f * 16 + lr] =
                            __half_as_ushort(__float2half_rn(acc[f][r] + bv));
                }
            }
        } else {
            int off = (y == 1) ? 0 : 64;
            #pragma unroll
            for (int f = 0; f < 4; ++f) {
                float bv = bias[f * 16 + lr];
                #pragma unroll
                for (int r = 0; r < 4; ++r) {
                    int gr = row0 + w * 16 + kq * 4 + r;
                    if (gr < M)
                        kvpk[(size_t)gr * 128 + off + f * 16 + lr] =
                            __half_as_ushort(__float2half_rn(acc[f][r] + bv));
                }
            }
        }
        __syncthreads();
    }
}

// ---------------- attention: wave per dst node, ELL adjacency, predicated gathers ------
__global__ __launch_bounds__(256) void attn_kernel(
    const unsigned short* __restrict__ qp, const unsigned short* __restrict__ sf16,
    const uint4* __restrict__ kv4,
    const int* __restrict__ deg, const int* __restrict__ slots,
    float* __restrict__ hout,
    unsigned short* __restrict__ h16,
    int n, int mode)
{
    __shared__ float lds[4][64 * 17];
    int node = (int)((blockIdx.x * (size_t)blockDim.x + threadIdx.x) >> 6);
    int lane = threadIdx.x & 63;
    int wl = threadIdx.x >> 6;
    if (node >= n) return;
    int h = lane >> 4, j = lane & 15;

    const uint4* q4 = (const uint4*)(qp + (size_t)node * 64 + h * 16);
    uint4 qa = q4[0], qb = q4[1];

    int dg = deg[node];
    if (dg > MAXDEG) dg = MAXDEG;
    const int* row = slots + (size_t)node * MAXDEG;
    float acc[16];
    #pragma unroll
    for (int c = 0; c < 16; ++c) acc[c] = 0.f;
    float dsum = 0.f;

    for (int eb = 0; eb < dg; eb += 16) {
        int e = eb + j;
        if (e < dg) {
            int src = row[e];
            const uint4* kvr = kv4 + (size_t)src * 16 + h * 2;
            uint4 ka = kvr[0], kb = kvr[1];
            uint4 va = kvr[8], vb = kvr[9];
            float s = 0.f;
            s = fdot2_acc(qa.x, ka.x, s);
            s = fdot2_acc(qa.y, ka.y, s);
            s = fdot2_acc(qa.z, ka.z, s);
            s = fdot2_acc(qa.w, ka.w, s);
            s = fdot2_acc(qb.x, kb.x, s);
            s = fdot2_acc(qb.y, kb.y, s);
            s = fdot2_acc(qb.z, kb.z, s);
            s = fdot2_acc(qb.w, kb.w, s);
            float p = __expf(s * 0.25f);
            dsum += p;
            unsigned uv[8] = {va.x, va.y, va.z, va.w, vb.x, vb.y, vb.z, vb.w};
            #pragma unroll
            for (int i = 0; i < 8; ++i) {
                __half2 hv = *(__half2*)&uv[i];
                acc[2 * i]     += p * __low2float(hv);
                acc[2 * i + 1] += p * __high2float(hv);
            }
        }
    }

    dsum += __shfl_xor(dsum, 1, 64);
    dsum += __shfl_xor(dsum, 2, 64);
    dsum += __shfl_xor(dsum, 4, 64);
    dsum += __shfl_xor(dsum, 8, 64);
    float inv = 1.f / (dsum + 1e-16f);

    float* L = lds[wl];
    int wb = lane * 17;
    #pragma unroll
    for (int c = 0; c < 16; ++c) L[wb + c] = acc[c];
    __builtin_amdgcn_wave_barrier();
    float sum = 0.f;
    int rb = (h * 16) * 17 + j;
    #pragma unroll
    for (int jj = 0; jj < 16; ++jj) sum += L[rb + jj * 17];

    float skip = __half2float(__ushort_as_half(sf16[(size_t)node * 64 + lane]));
    float outv = sum * inv + skip;
    if (mode == 1) {
        outv = fmaxf(outv, 0.f);
        h16[(size_t)node * 64 + lane] = __half_as_ushort(__float2half_rn(outv));
    } else {
        hout[(size_t)node * 64 + lane] = outv;
    }
}

// ---------------- fused pooling + head ----------------
__global__ __launch_bounds__(256) void poolhead_kernel(
    const float* __restrict__ h, const int* __restrict__ bm,
    const float* __restrict__ Wl, const float* __restrict__ bl,
    float* __restrict__ out)
{
    int g = blockIdx.x;
    int lo = 0, hi = N_NODES;
    while (lo < hi) { int mid = (lo + hi) >> 1; if (bm[mid] < g) lo = mid + 1; else hi = mid; }
    int s = lo;
    lo = 0; hi = N_NODES;
    while (lo < hi) { int mid = (lo + hi) >> 1; if (bm[mid] < g + 1) lo = mid + 1; else hi = mid; }
    int e = lo;

    int c = threadIdx.x & 63, sub = threadIdx.x >> 6;
    float sum = 0.f;
    for (int i = s + sub; i < e; i += 4) sum += h[(size_t)i * 64 + c];
    __shared__ float tmp[256];
    __shared__ float pl[64];
    tmp[threadIdx.x] = sum;
    __syncthreads();
    if (sub == 0) {
        sum = tmp[c] + tmp[c + 64] + tmp[c + 128] + tmp[c + 192];
        int cnt = e - s;
        pl[c] = sum / fmaxf((float)cnt, 1.0f);
    }
    __syncthreads();
    if (threadIdx.x < 64) {
        int lane = threadIdx.x;
        float logit = -INFINITY;
        if (lane < NCLS) {
            float acc = bl[lane];
            for (int k = 0; k < 64; ++k) acc += pl[k] * Wl[k * NCLS + lane];
            logit = acc;
        }
        float mx = logit;
        mx = fmaxf(mx, __shfl_xor(mx, 1, 64));
        mx = fmaxf(mx, __shfl_xor(mx, 2, 64));
        mx = fmaxf(mx, __shfl_xor(mx, 4, 64));
        mx = fmaxf(mx, __shfl_xor(mx, 8, 64));
        float ex = (lane < NCLS) ? __expf(logit - mx) : 0.f;
        float sm = ex;
        sm += __shfl_xor(sm, 1, 64);
        sm += __shfl_xor(sm, 2, 64);
        sm += __shfl_xor(sm, 4, 64);
        sm += __shfl_xor(sm, 8, 64);
        if (lane < NCLS) out[g * NCLS + lane] = ex / sm;
    }
}

// ---------------- launch ----------------
extern "C" void kernel_launch(void* const* d_in, const int* in_sizes, int n_in,
                              void* d_out, int out_size, void* d_ws, size_t ws_size,
                              hipStream_t stream) {
    const float* x  = (const float*)d_in[0];
    const int*   ei = (const int*)d_in[1];
    const int*   bm = (const int*)d_in[2];
    const float* W1[4] = {(const float*)d_in[3], (const float*)d_in[5], (const float*)d_in[7], (const float*)d_in[9]};
    const float* B1[4] = {(const float*)d_in[4], (const float*)d_in[6], (const float*)d_in[8], (const float*)d_in[10]};
    const float* W2[4] = {(const float*)d_in[11], (const float*)d_in[13], (const float*)d_in[15], (const float*)d_in[17]};
    const float* B2[4] = {(const float*)d_in[12], (const float*)d_in[14], (const float*)d_in[16], (const float*)d_in[18]};
    const float* W3[4] = {(const float*)d_in[19], (const float*)d_in[21], (const float*)d_in[23], (const float*)d_in[25]};
    const float* B3[4] = {(const float*)d_in[20], (const float*)d_in[22], (const float*)d_in[24], (const float*)d_in[26]};
    const float* Wl = (const float*)d_in[27];
    const float* bl = (const float*)d_in[28];
    float* outp = (float*)d_out;

    // workspace layout
    float* hf     = (float*)d_ws;                                 // NPAD*64 f32
    unsigned short* qp16 = (unsigned short*)(hf + (size_t)NPAD * 64); // NPAD*64 fp16
    unsigned short* sf16 = qp16 + (size_t)NPAD * 64;              // NPAD*64 fp16
    unsigned short* kvpk = sf16 + (size_t)NPAD * 64;              // NPAD*128 fp16
    unsigned short* xf16 = kvpk + (size_t)NPAD * 128;             // NPAD*128 fp16
    unsigned short* hs16 = xf16 + (size_t)NPAD * 128;             // NPAD*64 fp16
    unsigned short* wt_h = hs16 + (size_t)NPAD * 64;              // 3 * 32768
    int* deg     = (int*)(wt_h + 3 * 32768);                      // N (memset 200 KB)
    int* slots   = deg + N_NODES;                                 // N * MAXDEG

    const int* srcp = ei;
    const int* dstp = ei + N_EDGES;

    int n4x = N_NODES * F_IN / 4;
    int ggrid = 8 * XCHUNK;                      // 784 (fused-y)
    int agrid = (N_NODES + 3) / 4;
    size_t smem1  = (size_t)2 * 64 * F_IN * 2;   // 32 KB (A+B, K=128)
    size_t smem23 = (size_t)2 * 64 * HC * 2;     // 16 KB (A+B, K=64)

    // 1) zero degree counters (200 KB — cheap)
    hipMemsetAsync(deg, 0, N_NODES * sizeof(int), stream);

    // 2) merged ELL build + conversions (all independent)
    int ecgrid = SCB + 256 + (n4x + 255) / 256;
    ellconv_kernel<<<ecgrid, 256, 0, stream>>>(
        srcp, dstp, deg, slots,
        x, xf16, n4x,
        W1[0], W1[1], W1[2], W1[3],
        W2[0], W2[1], W2[2], W2[3],
        W3[0], W3[1], W3[2], W3[3],
        wt_h);

    // layer 1
    mfma_gemm_kernel<<<ggrid, 256, smem1, stream>>>(xf16,
        wt_h + 0 * 32768,
        B1[0], B1[1], B1[2], B1[3], qp16, sf16, kvpk, N_NODES, F_IN);
    attn_kernel<<<agrid, 256, 0, stream>>>(qp16, sf16, (const uint4*)kvpk, deg, slots,
                                           nullptr, hs16, N_NODES, 1);
    // layer 2
    mfma_gemm_kernel<<<ggrid, 256, smem23, stream>>>(hs16,
        wt_h + 1 * 32768,
        B2[0], B2[1], B2[2], B2[3], qp16, sf16, kvpk, N_NODES, HC);
    attn_kernel<<<agrid, 256, 0, stream>>>(qp16, sf16, (const uint4*)kvpk, deg, slots,
                                           nullptr, hs16, N_NODES, 1);
    // layer 3
    mfma_gemm_kernel<<<ggrid, 256, smem23, stream>>>(hs16,
        wt_h + 2 * 32768,
        B3[0], B3[1], B3[2], B3[3], qp16, sf16, kvpk, N_NODES, HC);
    attn_kernel<<<agrid, 256, 0, stream>>>(qp16, sf16, (const uint4*)kvpk, deg, slots,
                                           hf, nullptr, N_NODES, 0);

    // fused pooling + head
    poolhead_kernel<<<NG, 256, 0, stream>>>(hf, bm, Wl, bl, outp);
}

// Round 19
// 240.899 us; speedup vs baseline: 1.0673x; 1.0673x over previous
//
#include <hip/hip_runtime.h>
#include <hip/hip_fp16.h>
#include <math.h>

#define N_NODES 50000
#define NPAD    50048
#define N_EDGES 800000
#define F_IN    128
#define HC      64
#define NG      128
#define NCLS    10
#define NXT     782      // ceil(N_NODES/64) row tiles
#define XCHUNK  98       // ceil(NXT/8) tiles per XCD
#define DRANGE  6250     // N_NODES / 8 dst-range per XCD group
#define SCB     2048     // ELL-build block count (multiple of 8)
#define MAXDEG  64       // ELL row capacity (Poisson(16) max over 50k ~ 45)

typedef __attribute__((ext_vector_type(8))) _Float16 f16x8;  // 8 fp16 (4 VGPR)
typedef __attribute__((ext_vector_type(4))) float f32x4;
typedef _Float16 half2v __attribute__((ext_vector_type(2)));

__device__ __forceinline__ float fdot2_acc(unsigned a, unsigned b, float c) {
#if __has_builtin(__builtin_amdgcn_fdot2)
    half2v ha, hb;
    __builtin_memcpy(&ha, &a, 4);
    __builtin_memcpy(&hb, &b, 4);
    return __builtin_amdgcn_fdot2(ha, hb, c, false);
#else
    __half2 ha = *(__half2*)&a, hb = *(__half2*)&b;
    return c + __low2float(ha) * __low2float(hb) + __high2float(ha) * __high2float(hb);
#endif
}

// ================= ELL adjacency build (single pass) =================
__device__ __forceinline__ void ell_body(int bid, const int* __restrict__ src,
                                         const int* __restrict__ dst,
                                         int* __restrict__ deg,
                                         int* __restrict__ slots) {
    int grp = bid & 7;
    int nb = SCB >> 3;
    int slot = bid >> 3;
    int lo = grp * DRANGE, hi = lo + DRANGE;
    const int4* d4p = (const int4*)dst;
    const int4* s4p = (const int4*)src;
    int nchunks = N_EDGES >> 2;
    for (int t = slot * 256 + (int)threadIdx.x; t < nchunks; t += nb * 256) {
        int4 d = d4p[t];
        bool v0 = (d.x >= lo && d.x < hi);
        bool v1 = (d.y >= lo && d.y < hi);
        bool v2 = (d.z >= lo && d.z < hi);
        bool v3 = (d.w >= lo && d.w < hi);
        if (!(v0 | v1 | v2 | v3)) continue;   // skip src-stream load
        int4 s = s4p[t];
        if (v0) { int r = atomicAdd(&deg[d.x], 1); if (r < MAXDEG) slots[d.x * MAXDEG + r] = s.x; }
        if (v1) { int r = atomicAdd(&deg[d.y], 1); if (r < MAXDEG) slots[d.y * MAXDEG + r] = s.y; }
        if (v2) { int r = atomicAdd(&deg[d.z], 1); if (r < MAXDEG) slots[d.z * MAXDEG + r] = s.z; }
        if (v3) { int r = atomicAdd(&deg[d.w], 1); if (r < MAXDEG) slots[d.w * MAXDEG + r] = s.w; }
    }
}

// merged: ELL build + weight conversion + x cast (all independent)
__global__ __launch_bounds__(256) void ellconv_kernel(
    const int* __restrict__ src, const int* __restrict__ dst,
    int* __restrict__ deg, int* __restrict__ slots,
    const float* __restrict__ x, unsigned short* __restrict__ xf16, int n4x,
    const float* __restrict__ W10, const float* __restrict__ W11,
    const float* __restrict__ W12, const float* __restrict__ W13,
    const float* __restrict__ W20, const float* __restrict__ W21,
    const float* __restrict__ W22, const float* __restrict__ W23,
    const float* __restrict__ W30, const float* __restrict__ W31,
    const float* __restrict__ W32, const float* __restrict__ W33,
    unsigned short* __restrict__ wt_h)
{
    int bid = blockIdx.x;
    if (bid < SCB) {
        ell_body(bid, src, dst, deg, slots);
    } else if (bid < SCB + 256) {
        int idx = (bid - SCB) * 256 + threadIdx.x;   // [0, 65536)
        const float* W;
        int K, dbase, rr;
        if (idx < 32768) {
            int mat = idx >> 13; rr = idx & 8191; K = 128;
            W = (mat == 0) ? W10 : (mat == 1) ? W11 : (mat == 2) ? W12 : W13;
            dbase = 0 * 32768 + mat * 8192;
        } else if (idx < 49152) {
            int i2 = idx - 32768;
            int mat = i2 >> 12; rr = i2 & 4095; K = 64;
            W = (mat == 0) ? W20 : (mat == 1) ? W21 : (mat == 2) ? W22 : W23;
            dbase = 1 * 32768 + mat * 4096;
        } else {
            int i3 = idx - 49152;
            int mat = i3 >> 12; rr = i3 & 4095; K = 64;
            W = (mat == 0) ? W30 : (mat == 1) ? W31 : (mat == 2) ? W32 : W33;
            dbase = 2 * 32768 + mat * 4096;
        }
        int k = rr >> 6, c = rr & 63;
        float f = W[k * 64 + c];
        wt_h[dbase + c * K + k] = __half_as_ushort(__float2half_rn(f));
    } else {
        int t = (bid - SCB - 256) * 256 + threadIdx.x;
        if (t < n4x) {
            float4 f = ((const float4*)x)[t];
            ushort4 u;
            u.x = __half_as_ushort(__float2half_rn(f.x));
            u.y = __half_as_ushort(__float2half_rn(f.y));
            u.z = __half_as_ushort(__float2half_rn(f.z));
            u.w = __half_as_ushort(__float2half_rn(f.w));
            ((ushort4*)xf16)[t] = u;
        }
    }
}

// ================= single-pass fp16 MFMA GEMM (LDS-staged, split-y: R16 proven) ========
__device__ __forceinline__ void gemm_epilogue(int y, int row0, int w, int lr, int kq,
    f32x4* acc,
    const float* __restrict__ b0, const float* __restrict__ b1,
    const float* __restrict__ b2, const float* __restrict__ b3,
    unsigned short* __restrict__ qp16, unsigned short* __restrict__ sf16,
    unsigned short* __restrict__ kvpk, int M)
{
    const float* bias = (y == 0) ? b0 : (y == 1) ? b1 : (y == 2) ? b2 : b3;
    if (y == 0 || y == 3) {
        unsigned short* dstp = (y == 0) ? qp16 : sf16;
        #pragma unroll
        for (int f = 0; f < 4; ++f) {
            float bv = bias[f * 16 + lr];
            #pragma unroll
            for (int r = 0; r < 4; ++r) {
                int gr = row0 + w * 16 + kq * 4 + r;
                if (gr < M)
                    dstp[(size_t)gr * 64 + f * 16 + lr] =
                        __half_as_ushort(__float2half_rn(acc[f][r] + bv));
            }
        }
    } else {
        int off = (y == 1) ? 0 : 64;
        #pragma unroll
        for (int f = 0; f < 4; ++f) {
            float bv = bias[f * 16 + lr];
            #pragma unroll
            for (int r = 0; r < 4; ++r) {
                int gr = row0 + w * 16 + kq * 4 + r;
                if (gr < M)
                    kvpk[(size_t)gr * 128 + off + f * 16 + lr] =
                        __half_as_ushort(__float2half_rn(acc[f][r] + bv));
            }
        }
    }
}

__global__ __launch_bounds__(256) void mfma_gemm_kernel(
    const unsigned short* __restrict__ A16, const unsigned short* __restrict__ Wt_h,
    const float* __restrict__ b0, const float* __restrict__ b1,
    const float* __restrict__ b2, const float* __restrict__ b3,
    unsigned short* __restrict__ qp16, unsigned short* __restrict__ sf16,
    unsigned short* __restrict__ kvpk, int M, int K)
{
    extern __shared__ char smem[];
    int bid = blockIdx.x;
    int xcd = bid & 7;
    int slot = bid >> 3;
    int xt = xcd * XCHUNK + (slot >> 2);
    int y = slot & 3;
    if (xt >= NXT) return;
    int row0 = xt * 64;

    const int tileB = 64 * K * 2;
    char* sA  = smem;
    char* sBh = smem + tileB;

    int tid = threadIdx.x;
    int cpr = K >> 3;
    int total = 64 * cpr;
    const f16x8* gA  = (const f16x8*)(A16 + (size_t)row0 * K);
    const f16x8* gBh = (const f16x8*)(Wt_h + (size_t)y * 64 * K);
    for (int t = tid; t < total; t += 256) {
        int row = t / cpr, cs = t - row * cpr;
        int dstB = row * (K * 2) + ((cs * 16) ^ ((row & 7) << 4));
        *(f16x8*)(sA + dstB)  = gA[t];
        *(f16x8*)(sBh + dstB) = gBh[t];
    }
    __syncthreads();

    int w = tid >> 6, lane = tid & 63, lr = lane & 15, kq = lane >> 4;
    f32x4 acc[4];
    #pragma unroll
    for (int f = 0; f < 4; ++f) acc[f] = (f32x4){0.f, 0.f, 0.f, 0.f};

    int arow = w * 16 + lr;
    int abase = arow * (K * 2);
    int aswz = (arow & 7) << 4;
    for (int ks = 0; ks < K; ks += 32) {
        int kb = ks * 2 + kq * 16;
        f16x8 a = *(const f16x8*)(sA + abase + (kb ^ aswz));
        #pragma unroll
        for (int f = 0; f < 4; ++f) {
            int brow = f * 16 + lr;
            int boff = brow * (K * 2) + (kb ^ ((brow & 7) << 4));
            f16x8 bh = *(const f16x8*)(sBh + boff);
            acc[f] = __builtin_amdgcn_mfma_f32_16x16x32_f16(a, bh, acc[f], 0, 0, 0);
        }
    }
    gemm_epilogue(y, row0, w, lr, kq, acc, b0, b1, b2, b3, qp16, sf16, kvpk, M);
}

// ---------------- attention: wave per dst node, ELL adjacency, predicated gathers ------
__global__ __launch_bounds__(256) void attn_kernel(
    const unsigned short* __restrict__ qp, const unsigned short* __restrict__ sf16,
    const uint4* __restrict__ kv4,
    const int* __restrict__ deg, const int* __restrict__ slots,
    float* __restrict__ hout,
    unsigned short* __restrict__ h16,
    int n, int mode)
{
    __shared__ float lds[4][64 * 17];
    int node = (int)((blockIdx.x * (size_t)blockDim.x + threadIdx.x) >> 6);
    int lane = threadIdx.x & 63;
    int wl = threadIdx.x >> 6;
    if (node >= n) return;
    int h = lane >> 4, j = lane & 15;

    const uint4* q4 = (const uint4*)(qp + (size_t)node * 64 + h * 16);
    uint4 qa = q4[0], qb = q4[1];

    int dg = deg[node];
    if (dg > MAXDEG) dg = MAXDEG;
    const int* row = slots + (size_t)node * MAXDEG;
    float acc[16];
    #pragma unroll
    for (int c = 0; c < 16; ++c) acc[c] = 0.f;
    float dsum = 0.f;

    for (int eb = 0; eb < dg; eb += 16) {
        int e = eb + j;
        if (e < dg) {
            int src = row[e];
            const uint4* kvr = kv4 + (size_t)src * 16 + h * 2;
            uint4 ka = kvr[0], kb = kvr[1];
            uint4 va = kvr[8], vb = kvr[9];
            float s = 0.f;
            s = fdot2_acc(qa.x, ka.x, s);
            s = fdot2_acc(qa.y, ka.y, s);
            s = fdot2_acc(qa.z, ka.z, s);
            s = fdot2_acc(qa.w, ka.w, s);
            s = fdot2_acc(qb.x, kb.x, s);
            s = fdot2_acc(qb.y, kb.y, s);
            s = fdot2_acc(qb.z, kb.z, s);
            s = fdot2_acc(qb.w, kb.w, s);
            float p = __expf(s * 0.25f);
            dsum += p;
            unsigned uv[8] = {va.x, va.y, va.z, va.w, vb.x, vb.y, vb.z, vb.w};
            #pragma unroll
            for (int i = 0; i < 8; ++i) {
                __half2 hv = *(__half2*)&uv[i];
                acc[2 * i]     += p * __low2float(hv);
                acc[2 * i + 1] += p * __high2float(hv);
            }
        }
    }

    dsum += __shfl_xor(dsum, 1, 64);
    dsum += __shfl_xor(dsum, 2, 64);
    dsum += __shfl_xor(dsum, 4, 64);
    dsum += __shfl_xor(dsum, 8, 64);
    float inv = 1.f / (dsum + 1e-16f);

    float* L = lds[wl];
    int wb = lane * 17;
    #pragma unroll
    for (int c = 0; c < 16; ++c) L[wb + c] = acc[c];
    __builtin_amdgcn_wave_barrier();
    float sum = 0.f;
    int rb = (h * 16) * 17 + j;
    #pragma unroll
    for (int jj = 0; jj < 16; ++jj) sum += L[rb + jj * 17];

    float skip = __half2float(__ushort_as_half(sf16[(size_t)node * 64 + lane]));
    float outv = sum * inv + skip;
    if (mode == 1) {
        outv = fmaxf(outv, 0.f);
        h16[(size_t)node * 64 + lane] = __half_as_ushort(__float2half_rn(outv));
    } else {
        hout[(size_t)node * 64 + lane] = outv;
    }
}

// ---------------- fused pooling + head ----------------
__global__ __launch_bounds__(256) void poolhead_kernel(
    const float* __restrict__ h, const int* __restrict__ bm,
    const float* __restrict__ Wl, const float* __restrict__ bl,
    float* __restrict__ out)
{
    int g = blockIdx.x;
    int lo = 0, hi = N_NODES;
    while (lo < hi) { int mid = (lo + hi) >> 1; if (bm[mid] < g) lo = mid + 1; else hi = mid; }
    int s = lo;
    lo = 0; hi = N_NODES;
    while (lo < hi) { int mid = (lo + hi) >> 1; if (bm[mid] < g + 1) lo = mid + 1; else hi = mid; }
    int e = lo;

    int c = threadIdx.x & 63, sub = threadIdx.x >> 6;
    float sum = 0.f;
    for (int i = s + sub; i < e; i += 4) sum += h[(size_t)i * 64 + c];
    __shared__ float tmp[256];
    __shared__ float pl[64];
    tmp[threadIdx.x] = sum;
    __syncthreads();
    if (sub == 0) {
        sum = tmp[c] + tmp[c + 64] + tmp[c + 128] + tmp[c + 192];
        int cnt = e - s;
        pl[c] = sum / fmaxf((float)cnt, 1.0f);
    }
    __syncthreads();
    if (threadIdx.x < 64) {
        int lane = threadIdx.x;
        float logit = -INFINITY;
        if (lane < NCLS) {
            float acc = bl[lane];
            for (int k = 0; k < 64; ++k) acc += pl[k] * Wl[k * NCLS + lane];
            logit = acc;
        }
        float mx = logit;
        mx = fmaxf(mx, __shfl_xor(mx, 1, 64));
        mx = fmaxf(mx, __shfl_xor(mx, 2, 64));
        mx = fmaxf(mx, __shfl_xor(mx, 4, 64));
        mx = fmaxf(mx, __shfl_xor(mx, 8, 64));
        float ex = (lane < NCLS) ? __expf(logit - mx) : 0.f;
        float sm = ex;
        sm += __shfl_xor(sm, 1, 64);
        sm += __shfl_xor(sm, 2, 64);
        sm += __shfl_xor(sm, 4, 64);
        sm += __shfl_xor(sm, 8, 64);
        if (lane < NCLS) out[g * NCLS + lane] = ex / sm;
    }
}

// ---------------- launch ----------------
extern "C" void kernel_launch(void* const* d_in, const int* in_sizes, int n_in,
                              void* d_out, int out_size, void* d_ws, size_t ws_size,
                              hipStream_t stream) {
    const float* x  = (const float*)d_in[0];
    const int*   ei = (const int*)d_in[1];
    const int*   bm = (const int*)d_in[2];
    const float* W1[4] = {(const float*)d_in[3], (const float*)d_in[5], (const float*)d_in[7], (const float*)d_in[9]};
    const float* B1[4] = {(const float*)d_in[4], (const float*)d_in[6], (const float*)d_in[8], (const float*)d_in[10]};
    const float* W2[4] = {(const float*)d_in[11], (const float*)d_in[13], (const float*)d_in[15], (const float*)d_in[17]};
    const float* B2[4] = {(const float*)d_in[12], (const float*)d_in[14], (const float*)d_in[16], (const float*)d_in[18]};
    const float* W3[4] = {(const float*)d_in[19], (const float*)d_in[21], (const float*)d_in[23], (const float*)d_in[25]};
    const float* B3[4] = {(const float*)d_in[20], (const float*)d_in[22], (const float*)d_in[24], (const float*)d_in[26]};
    const float* Wl = (const float*)d_in[27];
    const float* bl = (const float*)d_in[28];
    float* outp = (float*)d_out;

    // workspace layout
    float* hf     = (float*)d_ws;                                 // NPAD*64 f32
    unsigned short* qp16 = (unsigned short*)(hf + (size_t)NPAD * 64); // NPAD*64 fp16
    unsigned short* sf16 = qp16 + (size_t)NPAD * 64;              // NPAD*64 fp16
    unsigned short* kvpk = sf16 + (size_t)NPAD * 64;              // NPAD*128 fp16
    unsigned short* xf16 = kvpk + (size_t)NPAD * 128;             // NPAD*128 fp16
    unsigned short* hs16 = xf16 + (size_t)NPAD * 128;             // NPAD*64 fp16
    unsigned short* wt_h = hs16 + (size_t)NPAD * 64;              // 3 * 32768
    int* deg     = (int*)(wt_h + 3 * 32768);                      // N (memset 200 KB)
    int* slots   = deg + N_NODES;                                 // N * MAXDEG

    const int* srcp = ei;
    const int* dstp = ei + N_EDGES;

    int n4x = N_NODES * F_IN / 4;
    int ggrid = 8 * XCHUNK * 4;                  // 3136 (split-y)
    int agrid = (N_NODES + 3) / 4;
    size_t smem1  = (size_t)2 * 64 * F_IN * 2;   // 32 KB (A+B, K=128)
    size_t smem23 = (size_t)2 * 64 * HC * 2;     // 16 KB (A+B, K=64)

    // 1) zero degree counters (200 KB — cheap)
    hipMemsetAsync(deg, 0, N_NODES * sizeof(int), stream);

    // 2) merged ELL build + conversions (all independent)
    int ecgrid = SCB + 256 + (n4x + 255) / 256;
    ellconv_kernel<<<ecgrid, 256, 0, stream>>>(
        srcp, dstp, deg, slots,
        x, xf16, n4x,
        W1[0], W1[1], W1[2], W1[3],
        W2[0], W2[1], W2[2], W2[3],
        W3[0], W3[1], W3[2], W3[3],
        wt_h);

    // layer 1
    mfma_gemm_kernel<<<ggrid, 256, smem1, stream>>>(xf16,
        wt_h + 0 * 32768,
        B1[0], B1[1], B1[2], B1[3], qp16, sf16, kvpk, N_NODES, F_IN);
    attn_kernel<<<agrid, 256, 0, stream>>>(qp16, sf16, (const uint4*)kvpk, deg, slots,
                                           nullptr, hs16, N_NODES, 1);
    // layer 2
    mfma_gemm_kernel<<<ggrid, 256, smem23, stream>>>(hs16,
        wt_h + 1 * 32768,
        B2[0], B2[1], B2[2], B2[3], qp16, sf16, kvpk, N_NODES, HC);
    attn_kernel<<<agrid, 256, 0, stream>>>(qp16, sf16, (const uint4*)kvpk, deg, slots,
                                           nullptr, hs16, N_NODES, 1);
    // layer 3
    mfma_gemm_kernel<<<ggrid, 256, smem23, stream>>>(hs16,
        wt_h + 2 * 32768,
        B3[0], B3[1], B3[2], B3[3], qp16, sf16, kvpk, N_NODES, HC);
    attn_kernel<<<agrid, 256, 0, stream>>>(qp16, sf16, (const uint4*)kvpk, deg, slots,
                                           hf, nullptr, N_NODES, 0);

    // fused pooling + head
    poolhead_kernel<<<NG, 256, 0, stream>>>(hf, bm, Wl, bl, outp);
}